// Round 16
// baseline (142.898 us; speedup 1.0000x reference)
//
#include <hip/hip_runtime.h>
#include <hip/hip_fp16.h>
#include <cstdint>
#include <cstddef>

#define DMODEL 1024
#define NHEADS 16
#define DKH    64
#define SEQT   2048
#define NBATCH 2
#define MTOT   (NBATCH*SEQT)   // 4096

// 0.125 * log2(e): folds sm_scale and the exp->exp2 conversion into Q.
#define QSCALE 0.1803368801111204f

using h16   = _Float16;
using h16x2 = __attribute__((ext_vector_type(2))) h16;
using h16x4 = __attribute__((ext_vector_type(4))) h16;
using h16x8 = __attribute__((ext_vector_type(8))) h16;
using f32x4 = __attribute__((ext_vector_type(4))) float;
using fp16x2_native = __attribute__((ext_vector_type(2))) __fp16;

using as1_void = __attribute__((address_space(1))) void;
using as3_void = __attribute__((address_space(3))) void;

__device__ __forceinline__ void gll16(void* lds, const void* g) {
  __builtin_amdgcn_global_load_lds((const as1_void*)g, (as3_void*)lds, 16, 0, 0);
}

__device__ __forceinline__ h16x2 pkrtz(float a, float b) {
  fp16x2_native t = __builtin_amdgcn_cvt_pkrtz(a, b);
  h16x2 r; r[0] = (h16)t[0]; r[1] = (h16)t[1]; return r;
}

__device__ __forceinline__ h16 hx2exp(h16 x) {   // v_exp_f16
  __half r = hexp2(*(__half*)&x);
  return *(h16*)&r;
}

__device__ __forceinline__ h16x4 cvt4(const float4 v) {
  h16x4 o; o[0] = (h16)v.x; o[1] = (h16)v.y; o[2] = (h16)v.z; o[3] = (h16)v.w; return o;
}

// ---------------------------------------------------------------- prep ----
__global__ void prep_kernel(const float4* __restrict__ x,
                            const float4* __restrict__ Wq, const float4* __restrict__ Wk,
                            const float4* __restrict__ Wv, const float4* __restrict__ Wo,
                            h16x4* __restrict__ xb,
                            h16x4* __restrict__ wqb, h16x4* __restrict__ wkb,
                            h16x4* __restrict__ wvb, h16x4* __restrict__ wob,
                            float* __restrict__ ctab, float* __restrict__ stab) {
  const int tid  = blockIdx.x * blockDim.x + threadIdx.x;
  const int nthr = gridDim.x * blockDim.x;
  const int NX4 = MTOT * DMODEL / 4;
  const int NW4 = DMODEL * DMODEL / 4;
  for (int i = tid; i < NX4; i += nthr) xb[i] = cvt4(x[i]);
  for (int i = tid; i < NW4; i += nthr) {
    wqb[i] = cvt4(Wq[i]);
    wkb[i] = cvt4(Wk[i]);
    wvb[i] = cvt4(Wv[i]);
    wob[i] = cvt4(Wo[i]);
  }
  for (int i = tid; i < SEQT * 32; i += nthr) {
    const int t = i >> 5, fi = i & 31;
    float inv = __expf(-0.28782313662425575f * (float)fi);
    float ang = (float)t * inv;
    float s, c;
    sincosf(ang, &s, &c);
    ctab[i] = c; stab[i] = s;
  }
}

// --------------------------------------------------- 128x128 B^T GEMM ----
__device__ __forceinline__ void gemm128_bt(const h16* __restrict__ A, const h16* __restrict__ Bt,
                                           int m0, int n0, h16* Al, h16* Bl, f32x4 acc[4][4]) {
  const int tid  = threadIdx.x;
  const int lane = tid & 63;
  const int wv   = tid >> 6;
  const int wm = (wv >> 1) * 64, wn = (wv & 1) * 64;
  const int lr = lane & 15, lk = (lane >> 4) * 8;
  const int srow = tid >> 2, scol = (tid & 3) * 8;
  const h16* a0 = A  + (size_t)(m0 + srow) * DMODEL + scol;
  const h16* a1 = a0 + (size_t)64 * DMODEL;
  const h16* b0 = Bt + (size_t)(n0 + srow) * DMODEL + scol;
  const h16* b1 = b0 + (size_t)64 * DMODEL;
  h16* alds0 = Al + wv * 512;
  h16* alds1 = Al + 2048 + wv * 512;
  h16* blds0 = Bl + wv * 512;
  h16* blds1 = Bl + 2048 + wv * 512;

  for (int k0 = 0; k0 < DMODEL; k0 += 32) {
    __syncthreads();
    gll16(alds0, a0 + k0);
    gll16(alds1, a1 + k0);
    gll16(blds0, b0 + k0);
    gll16(blds1, b1 + k0);
    __syncthreads();
    h16x8 af[4], bfr[4];
#pragma unroll
    for (int i = 0; i < 4; ++i) {
      af[i]  = *(const h16x8*)(Al + (wm + i * 16 + lr) * 32 + lk);
      bfr[i] = *(const h16x8*)(Bl + (wn + i * 16 + lr) * 32 + lk);
    }
#pragma unroll
    for (int i = 0; i < 4; ++i)
#pragma unroll
      for (int j = 0; j < 4; ++j)
        acc[i][j] = __builtin_amdgcn_mfma_f32_16x16x32_f16(af[i], bfr[j], acc[i][j], 0, 0, 0);
  }
}

// ----------------------------------------------------------------- qkv ----
__global__ __launch_bounds__(256, 2) void qkv_kernel(
    const h16* __restrict__ xb,
    const h16* __restrict__ wqb, const h16* __restrict__ wkb, const h16* __restrict__ wvb,
    const float* __restrict__ ctab, const float* __restrict__ stab,
    h16* __restrict__ Qb, h16* __restrict__ Kb, h16* __restrict__ Vt) {
  __shared__ h16 Al[128 * 32], Bl[128 * 32];
  const int which = blockIdx.z;
  const h16* W = (which == 0) ? wqb : (which == 1) ? wkb : wvb;
  const int m0 = blockIdx.x * 128, n0 = blockIdx.y * 128;
  f32x4 acc[4][4];
  const f32x4 zero4 = {0.f, 0.f, 0.f, 0.f};
#pragma unroll
  for (int i = 0; i < 4; ++i)
#pragma unroll
    for (int j = 0; j < 4; ++j) acc[i][j] = zero4;

  gemm128_bt(xb, W, m0, n0, Al, Bl, acc);

  const int lane = threadIdx.x & 63, wv = threadIdx.x >> 6;
  const int wm = (wv >> 1) * 64, wn = (wv & 1) * 64;
  const int lr4 = ((lane >> 4) << 2), lc = lane & 15;
  if (which == 2) {
    // V stored transposed [B][H][D][T]; r is contiguous in t -> h16x4 store.
#pragma unroll
    for (int i = 0; i < 4; ++i) {
      const int m = m0 + wm + i * 16 + lr4;
      const int b = m >> 11, t = m & (SEQT - 1);
#pragma unroll
      for (int j = 0; j < 4; ++j) {
        const int n = n0 + wn + j * 16 + lc;
        const int h = n >> 6, d = n & 63;
        h16x4 o4;
#pragma unroll
        for (int r = 0; r < 4; ++r) o4[r] = (h16)acc[i][j][r];
        *(h16x4*)&Vt[((size_t)(b * NHEADS + h) * DKH + d) * SEQT + t] = o4;
      }
    }
  } else {
#pragma unroll
    for (int i = 0; i < 4; ++i) {
#pragma unroll
      for (int j = 0; j < 4; ++j) {
        const int n = n0 + wn + j * 16 + lc;
        const int h = n >> 6, d = n & 63;
#pragma unroll
        for (int r = 0; r < 4; ++r) {
          const int m = m0 + wm + i * 16 + lr4 + r;
          const int b = m >> 11, t = m & (SEQT - 1);
          float v = acc[i][j][r];
          float pv = __shfl_xor(v, 1);
          const int fi = d >> 1;
          float c = ctab[t * 32 + fi], s = stab[t * 32 + fi];
          float res = (d & 1) ? (v * c + pv * s) : (v * c - pv * s);
          if (which == 0) res *= QSCALE;   // fold sm_scale*log2e into Q
          h16* dst = (which == 0) ? Qb : Kb;
          dst[((size_t)(b * NHEADS + h) * SEQT + t) * DKH + d] = (h16)res;
        }
      }
    }
  }
}

// ---------------------------------------------------------------- attn ----
// Intra-block split-K flash attention: QBLK=32, KBLK=64, 4 waves. Wave-pair
// p = wv&1 processes k-tiles kt = 2t+p into its OWN LDS K/V buffer (R11
// split-phase prefetch per pair); exact online-softmax merge of the two
// partials via LDS at the end. Why: R15's counters showed 23% time-avg
// occupancy (50% static) from the all-resident tail - short blocks retire
// and leave wave slots empty. Split-K halves max block depth (16->8 units)
// and doubles grid (2048 > 1024 resident slots) so a real queue refills
// slots. Packed-f16 softmax (R15), defer-max THR=9, conflict-free strides
// (76 h16 = 38 dw == 6 mod 32). XCD class v gets a in {v,15-v,16+v,31-v,
// 32+v,47-v,48+v,63-v}: exactly 132 tile-units per class.
__global__ __launch_bounds__(256, 4) void attn_kernel(
    const h16* __restrict__ Qb, const h16* __restrict__ Kg,
    const h16* __restrict__ Vt, h16* __restrict__ Mg) {
  __shared__ h16 KT[2][64][76];     // per-pair [key][d]
  __shared__ h16 VT[2][64][76];     // per-pair [d][key]
  const int linear = blockIdx.x + 64 * blockIdx.y;
  const int v  = linear & 7;         // XCD class
  const int pp = linear >> 3;        // 0..255
  const int bh = pp & 31;
  const int j  = ((pp >> 5) + bh) & 7;
  const int a  = (j & 1) ? ((j >> 1) * 16 + 15 - v) : ((j >> 1) * 16 + v);
  const int b = bh >> 4, h = bh & 15;
  const int tid = threadIdx.x, lane = tid & 63, wv = tid >> 6;
  const int pair = wv & 1, sub = wv >> 1;
  const int lr = lane & 15, lg = lane >> 4;
  const int q0 = a * 32;
  const int q  = q0 + sub * 16 + lr;       // this lane's q-row
  const int nkt = (a >> 1) + 1;            // 64-key tiles for causal range
  const int T   = (nkt + 1) >> 1;          // per-pair loop count
  const h16* Qp = Qb + ((size_t)bh * SEQT + q0 + sub * 16) * DKH;
  const h16* Kp = Kg + (size_t)bh * SEQT * DKH;
  const h16* Vp = Vt + (size_t)bh * DKH * SEQT;

  // Q as B-fragment of S^T = K·Q^T : col=q(lr), k=d(kk*32+lg*8+j)
  h16x8 qf[2];
#pragma unroll
  for (int kk = 0; kk < 2; ++kk)
    qf[kk] = *(const h16x8*)(Qp + lr * DKH + kk * 32 + lg * 8);

  float mrow = -3.0e38f, lsum = 0.f;
  f32x4 o[4];
  const f32x4 zero4 = {0.f, 0.f, 0.f, 0.f};
#pragma unroll
  for (int di = 0; di < 4; ++di) o[di] = zero4;

  // staging indices: pair's 128 threads cover a 64x64 h16 tile (64B each)
  const int tid2 = (sub << 6) | lane;      // 0..127 within pair
  const int srow = tid2 >> 1, scol = (tid2 & 1) * 32;
  uint4 ka0, ka1, ka2, ka3;   // K[kt+2] in flight (live across QK only)
  uint4 va0, va1, va2, va3;   // V[kt+2] in flight (live across softmax+PV)

#define KISSUE(k0_) {                                                      \
    const h16* kb_ = Kp + (size_t)((k0_) + srow) * DKH + scol;             \
    ka0 = *(const uint4*)(kb_);                                            \
    ka1 = *(const uint4*)(kb_ + 8);                                        \
    ka2 = *(const uint4*)(kb_ + 16);                                       \
    ka3 = *(const uint4*)(kb_ + 24);                                       \
  }
#define KWRITE() {                                                         \
    *(uint4*)&KT[pair][srow][scol]      = ka0;                             \
    *(uint4*)&KT[pair][srow][scol + 8]  = ka1;                             \
    *(uint4*)&KT[pair][srow][scol + 16] = ka2;                             \
    *(uint4*)&KT[pair][srow][scol + 24] = ka3;                             \
  }
#define VISSUE(k0_) {                                                      \
    const h16* vb_ = Vp + (size_t)srow * SEQT + (k0_) + scol;              \
    va0 = *(const uint4*)(vb_);                                            \
    va1 = *(const uint4*)(vb_ + 8);                                        \
    va2 = *(const uint4*)(vb_ + 16);                                       \
    va3 = *(const uint4*)(vb_ + 24);                                       \
  }
#define VWRITE() {                                                         \
    *(uint4*)&VT[pair][srow][scol]      = va0;                             \
    *(uint4*)&VT[pair][srow][scol + 8]  = va1;                             \
    *(uint4*)&VT[pair][srow][scol + 16] = va2;                             \
    *(uint4*)&VT[pair][srow][scol + 24] = va3;                             \
  }

  // prologue: each pair stages its first tile (guarded: pair1 may be empty)
  int kt = pair;
  if (kt < nkt) {
    KISSUE(kt * 64); VISSUE(kt * 64);
    KWRITE(); VWRITE();
  }
  __syncthreads();

  for (int t = 0; t < T; ++t, kt += 2) {
    const bool active = (kt < nkt);
    const bool hn = (kt + 2 < nkt);
    const int k0 = kt * 64;

    if (hn) { KISSUE((kt + 2) * 64); __builtin_amdgcn_sched_barrier(0); }

    // S^T tile: lane holds score(q, key = k0 + ni*16 + lg*4 + r)
    f32x4 s[4];
    if (active) {
      __builtin_amdgcn_s_setprio(1);
#pragma unroll
      for (int ni = 0; ni < 4; ++ni) {
        s[ni] = zero4;
#pragma unroll
        for (int kk = 0; kk < 2; ++kk) {
          h16x8 kf = *(const h16x8*)&KT[pair][ni * 16 + lr][kk * 32 + lg * 8];
          s[ni] = __builtin_amdgcn_mfma_f32_16x16x32_f16(kf, qf[kk], s[ni], 0, 0, 0);
        }
      }
      __builtin_amdgcn_s_setprio(0);
    }

    __syncthreads();   // A: pair done reading KT[pair]
    if (hn) {
      KWRITE();
      VISSUE((kt + 2) * 64); __builtin_amdgcn_sched_barrier(0);
    }

    if (active) {
      // causal mask only on the last tile (proof: only kt==nkt-1 can hold
      // keys > q for rows in [q0, q0+32))
      if (kt == nkt - 1) {
#pragma unroll
        for (int ni = 0; ni < 4; ++ni)
#pragma unroll
          for (int r = 0; r < 4; ++r) {
            const int key = k0 + ni * 16 + lg * 4 + r;
            if (key > q) s[ni][r] = -3.0e38f;
          }
      }

      // S -> packed f16
      h16x4 s16[4];
#pragma unroll
      for (int ni = 0; ni < 4; ++ni) {
        h16x2 lo = pkrtz(s[ni][0], s[ni][1]);
        h16x2 hi = pkrtz(s[ni][2], s[ni][3]);
        s16[ni][0] = lo[0]; s16[ni][1] = lo[1]; s16[ni][2] = hi[0]; s16[ni][3] = hi[1];
      }
      // lane-local max tree + 2 cross-lg shuffles
      h16x4 t0 = __builtin_elementwise_max(s16[0], s16[1]);
      h16x4 t1 = __builtin_elementwise_max(s16[2], s16[3]);
      h16x4 t4 = __builtin_elementwise_max(t0, t1);
      h16 mh = t4[0] > t4[1] ? t4[0] : t4[1];
      h16 m2 = t4[2] > t4[3] ? t4[2] : t4[3];
      mh = mh > m2 ? mh : m2;
      float mx = (float)mh;
      mx = fmaxf(mx, __shfl_xor(mx, 16));
      mx = fmaxf(mx, __shfl_xor(mx, 32));
      if (mx > mrow + 9.0f) {       // defer-max, f16-safe (P <= 512)
        const float scl = exp2f(mrow - mx);
        mrow = mx;
        lsum *= scl;
#pragma unroll
        for (int di = 0; di < 4; ++di)
#pragma unroll
          for (int r = 0; r < 4; ++r) o[di][r] *= scl;
      }
      const h16 m16 = (h16)mrow;
      h16x4 mv; mv[0] = m16; mv[1] = m16; mv[2] = m16; mv[3] = m16;
      h16x4 pb[4];
#pragma unroll
      for (int ni = 0; ni < 4; ++ni) {
        h16x4 d = s16[ni] - mv;
        pb[ni][0] = hx2exp(d[0]); pb[ni][1] = hx2exp(d[1]);
        pb[ni][2] = hx2exp(d[2]); pb[ni][3] = hx2exp(d[3]);
      }
      {
        h16x4 a4 = (pb[0] + pb[1]) + (pb[2] + pb[3]);
        float rs = (float)a4[0] + (float)a4[1] + (float)a4[2] + (float)a4[3];
        rs += __shfl_xor(rs, 16);
        rs += __shfl_xor(rs, 32);
        lsum += rs;
      }

      // PV: O^T = V^T · P^T via 16x16x16
      __builtin_amdgcn_s_setprio(1);
#pragma unroll
      for (int ni = 0; ni < 4; ++ni) {
#pragma unroll
        for (int di = 0; di < 4; ++di) {
          h16x4 va = *(const h16x4*)&VT[pair][di * 16 + lr][ni * 16 + lg * 4];
          o[di] = __builtin_amdgcn_mfma_f32_16x16x16f16(va, pb[ni], o[di], 0, 0, 0);
        }
      }
      __builtin_amdgcn_s_setprio(0);
    }

    __syncthreads();   // B: pair done reading VT[pair]; KT[pair] republished
    if (hn) VWRITE();
  }
#undef KISSUE
#undef KWRITE
#undef VISSUE
#undef VWRITE

  // ---- merge the two k-split partials (exact online-softmax combine) ----
  __syncthreads();
  float* mf = (float*)&KT[0][0][0];        // 32 x 64 f32 = 8KB (< 19456B)
  float* mm = mf + 2048;                    // 32 m
  float* ml = mm + 32;                      // 32 l
  const int row = sub * 16 + lr;
  if (pair == 1) {
#pragma unroll
    for (int di = 0; di < 4; ++di)
#pragma unroll
      for (int r = 0; r < 4; ++r)
        mf[row * 64 + di * 16 + lg * 4 + r] = o[di][r];
    if (lg == 0) { mm[row] = mrow; ml[row] = lsum; }
  }
  __syncthreads();
  h16* ob = &VT[0][0][0];                   // bounce tile [32][76] h16
  if (pair == 0) {
    const float m1 = mm[row], l1 = ml[row];
    const float mM = fmaxf(mrow, m1);
    const float c0 = exp2f(mrow - mM), c1 = exp2f(m1 - mM);
    const float inv = 1.0f / (lsum * c0 + l1 * c1);
#pragma unroll
    for (int di = 0; di < 4; ++di) {
      float r0 = (o[di][0] * c0 + mf[row * 64 + di * 16 + lg * 4 + 0] * c1) * inv;
      float r1 = (o[di][1] * c0 + mf[row * 64 + di * 16 + lg * 4 + 1] * c1) * inv;
      float r2 = (o[di][2] * c0 + mf[row * 64 + di * 16 + lg * 4 + 2] * c1) * inv;
      float r3 = (o[di][3] * c0 + mf[row * 64 + di * 16 + lg * 4 + 3] * c1) * inv;
      h16x2 lo = pkrtz(r0, r1);
      h16x2 hi = pkrtz(r2, r3);
      h16x4 o4; o4[0] = lo[0]; o4[1] = lo[1]; o4[2] = hi[0]; o4[3] = hi[1];
      *(h16x4*)&ob[row * 76 + di * 16 + lg * 4] = o4;
    }
  }
  __syncthreads();
  {
    const int orow = tid >> 3, c0b = (tid & 7) * 8;
    h16* dst = Mg + ((size_t)(b * SEQT + q0 + orow)) * DMODEL + h * DKH + c0b;
    *(uint4*)dst = *(const uint4*)&ob[orow * 76 + c0b];
  }
}

// ---------------------------------------------------------------- proj ----
__global__ __launch_bounds__(256, 2) void proj_kernel(
    const h16* __restrict__ Mg, const h16* __restrict__ wob, float* __restrict__ out) {
  __shared__ h16 Al[128 * 32], Bl[128 * 32];
  const int m0 = blockIdx.x * 128, n0 = blockIdx.y * 128;
  f32x4 acc[4][4];
  const f32x4 zero4 = {0.f, 0.f, 0.f, 0.f};
#pragma unroll
  for (int i = 0; i < 4; ++i)
#pragma unroll
    for (int j = 0; j < 4; ++j) acc[i][j] = zero4;

  gemm128_bt(Mg, wob, m0, n0, Al, Bl, acc);

  const int lane = threadIdx.x & 63, wv = threadIdx.x >> 6;
  const int wm = (wv >> 1) * 64, wn = (wv & 1) * 64;
  const int lr4 = ((lane >> 4) << 2), lc = lane & 15;
#pragma unroll
  for (int i = 0; i < 4; ++i)
#pragma unroll
    for (int j = 0; j < 4; ++j) {
      const int n = n0 + wn + j * 16 + lc;
#pragma unroll
      for (int r = 0; r < 4; ++r) {
        const int m = m0 + wm + i * 16 + lr4 + r;
        out[(size_t)m * DMODEL + n] = acc[i][j][r];
      }
    }
}

// -------------------------------------------------------------- launch ----
extern "C" void kernel_launch(void* const* d_in, const int* in_sizes, int n_in,
                              void* d_out, int out_size, void* d_ws, size_t ws_size,
                              hipStream_t stream) {
  (void)in_sizes; (void)n_in; (void)out_size; (void)ws_size;
  const float* x  = (const float*)d_in[0];
  const float* Wq = (const float*)d_in[1];
  const float* Wk = (const float*)d_in[2];
  const float* Wv = (const float*)d_in[3];
  const float* Wo = (const float*)d_in[4];
  float* out = (float*)d_out;

  char* w = (char*)d_ws;
  h16* xb  = (h16*)w; w += (size_t)MTOT * DMODEL * 2;
  h16* wqb = (h16*)w; w += (size_t)DMODEL * DMODEL * 2;
  h16* wkb = (h16*)w; w += (size_t)DMODEL * DMODEL * 2;
  h16* wvb = (h16*)w; w += (size_t)DMODEL * DMODEL * 2;
  h16* wob = (h16*)w; w += (size_t)DMODEL * DMODEL * 2;
  h16* Qb  = (h16*)w; w += (size_t)MTOT * DMODEL * 2;
  h16* Kb  = (h16*)w; w += (size_t)MTOT * DMODEL * 2;
  h16* Vt  = (h16*)w; w += (size_t)MTOT * DMODEL * 2;
  h16* Mg  = (h16*)w; w += (size_t)MTOT * DMODEL * 2;
  float* ctab = (float*)w; w += (size_t)SEQT * 32 * 4;
  float* stab = (float*)w; w += (size_t)SEQT * 32 * 4;

  prep_kernel<<<1024, 256, 0, stream>>>((const float4*)x, (const float4*)Wq, (const float4*)Wk,
                                        (const float4*)Wv, (const float4*)Wo,
                                        (h16x4*)xb, (h16x4*)wqb, (h16x4*)wkb, (h16x4*)wvb,
                                        (h16x4*)wob, ctab, stab);
  qkv_kernel<<<dim3(32, 8, 3), 256, 0, stream>>>(xb, wqb, wkb, wvb, ctab, stab, Qb, Kb, Vt);
  attn_kernel<<<dim3(64, 32), 256, 0, stream>>>(Qb, Kb, Vt, Mg);
  proj_kernel<<<dim3(32, 8), 256, 0, stream>>>(Mg, wob, out);
}

// Round 17
// 109.752 us; speedup vs baseline: 1.3020x; 1.3020x over previous
//
#include <hip/hip_runtime.h>
#include <hip/hip_fp16.h>
#include <cstdint>
#include <cstddef>

#define DMODEL 1024
#define NHEADS 16
#define DKH    64
#define SEQT   2048
#define NBATCH 2
#define MTOT   (NBATCH*SEQT)   // 4096

// 0.125 * log2(e): folds sm_scale and the exp->exp2 conversion into Q.
#define QSCALE 0.1803368801111204f

using h16   = _Float16;
using h16x2 = __attribute__((ext_vector_type(2))) h16;
using h16x4 = __attribute__((ext_vector_type(4))) h16;
using h16x8 = __attribute__((ext_vector_type(8))) h16;
using f32x4 = __attribute__((ext_vector_type(4))) float;
using fp16x2_native = __attribute__((ext_vector_type(2))) __fp16;

using as1_void = __attribute__((address_space(1))) void;
using as3_void = __attribute__((address_space(3))) void;

__device__ __forceinline__ void gll16(void* lds, const void* g) {
  __builtin_amdgcn_global_load_lds((const as1_void*)g, (as3_void*)lds, 16, 0, 0);
}

__device__ __forceinline__ h16x2 pkrtz(float a, float b) {
  fp16x2_native t = __builtin_amdgcn_cvt_pkrtz(a, b);
  h16x2 r; r[0] = (h16)t[0]; r[1] = (h16)t[1]; return r;
}

__device__ __forceinline__ h16 hx2exp(h16 x) {   // v_exp_f16
  __half r = hexp2(*(__half*)&x);
  return *(h16*)&r;
}

__device__ __forceinline__ h16x4 cvt4(const float4 v) {
  h16x4 o; o[0] = (h16)v.x; o[1] = (h16)v.y; o[2] = (h16)v.z; o[3] = (h16)v.w; return o;
}

// ---------------------------------------------------------------- prep ----
__global__ void prep_kernel(const float4* __restrict__ x,
                            const float4* __restrict__ Wq, const float4* __restrict__ Wk,
                            const float4* __restrict__ Wv, const float4* __restrict__ Wo,
                            h16x4* __restrict__ xb,
                            h16x4* __restrict__ wqb, h16x4* __restrict__ wkb,
                            h16x4* __restrict__ wvb, h16x4* __restrict__ wob,
                            float* __restrict__ ctab, float* __restrict__ stab) {
  const int tid  = blockIdx.x * blockDim.x + threadIdx.x;
  const int nthr = gridDim.x * blockDim.x;
  const int NX4 = MTOT * DMODEL / 4;
  const int NW4 = DMODEL * DMODEL / 4;
  for (int i = tid; i < NX4; i += nthr) xb[i] = cvt4(x[i]);
  for (int i = tid; i < NW4; i += nthr) {
    wqb[i] = cvt4(Wq[i]);
    wkb[i] = cvt4(Wk[i]);
    wvb[i] = cvt4(Wv[i]);
    wob[i] = cvt4(Wo[i]);
  }
  for (int i = tid; i < SEQT * 32; i += nthr) {
    const int t = i >> 5, fi = i & 31;
    float inv = __expf(-0.28782313662425575f * (float)fi);
    float ang = (float)t * inv;
    float s, c;
    sincosf(ang, &s, &c);
    ctab[i] = c; stab[i] = s;
  }
}

// --------------------------------------------------- 128x128 B^T GEMM ----
__device__ __forceinline__ void gemm128_bt(const h16* __restrict__ A, const h16* __restrict__ Bt,
                                           int m0, int n0, h16* Al, h16* Bl, f32x4 acc[4][4]) {
  const int tid  = threadIdx.x;
  const int lane = tid & 63;
  const int wv   = tid >> 6;
  const int wm = (wv >> 1) * 64, wn = (wv & 1) * 64;
  const int lr = lane & 15, lk = (lane >> 4) * 8;
  const int srow = tid >> 2, scol = (tid & 3) * 8;
  const h16* a0 = A  + (size_t)(m0 + srow) * DMODEL + scol;
  const h16* a1 = a0 + (size_t)64 * DMODEL;
  const h16* b0 = Bt + (size_t)(n0 + srow) * DMODEL + scol;
  const h16* b1 = b0 + (size_t)64 * DMODEL;
  h16* alds0 = Al + wv * 512;
  h16* alds1 = Al + 2048 + wv * 512;
  h16* blds0 = Bl + wv * 512;
  h16* blds1 = Bl + 2048 + wv * 512;

  for (int k0 = 0; k0 < DMODEL; k0 += 32) {
    __syncthreads();
    gll16(alds0, a0 + k0);
    gll16(alds1, a1 + k0);
    gll16(blds0, b0 + k0);
    gll16(blds1, b1 + k0);
    __syncthreads();
    h16x8 af[4], bfr[4];
#pragma unroll
    for (int i = 0; i < 4; ++i) {
      af[i]  = *(const h16x8*)(Al + (wm + i * 16 + lr) * 32 + lk);
      bfr[i] = *(const h16x8*)(Bl + (wn + i * 16 + lr) * 32 + lk);
    }
#pragma unroll
    for (int i = 0; i < 4; ++i)
#pragma unroll
      for (int j = 0; j < 4; ++j)
        acc[i][j] = __builtin_amdgcn_mfma_f32_16x16x32_f16(af[i], bfr[j], acc[i][j], 0, 0, 0);
  }
}

// ----------------------------------------------------------------- qkv ----
__global__ __launch_bounds__(256, 2) void qkv_kernel(
    const h16* __restrict__ xb,
    const h16* __restrict__ wqb, const h16* __restrict__ wkb, const h16* __restrict__ wvb,
    const float* __restrict__ ctab, const float* __restrict__ stab,
    h16* __restrict__ Qb, h16* __restrict__ Kb, h16* __restrict__ Vt) {
  __shared__ h16 Al[128 * 32], Bl[128 * 32];
  const int which = blockIdx.z;
  const h16* W = (which == 0) ? wqb : (which == 1) ? wkb : wvb;
  const int m0 = blockIdx.x * 128, n0 = blockIdx.y * 128;
  f32x4 acc[4][4];
  const f32x4 zero4 = {0.f, 0.f, 0.f, 0.f};
#pragma unroll
  for (int i = 0; i < 4; ++i)
#pragma unroll
    for (int j = 0; j < 4; ++j) acc[i][j] = zero4;

  gemm128_bt(xb, W, m0, n0, Al, Bl, acc);

  const int lane = threadIdx.x & 63, wv = threadIdx.x >> 6;
  const int wm = (wv >> 1) * 64, wn = (wv & 1) * 64;
  const int lr4 = ((lane >> 4) << 2), lc = lane & 15;
  if (which == 2) {
    // V stored transposed [B][H][D][T]; r is contiguous in t -> h16x4 store.
#pragma unroll
    for (int i = 0; i < 4; ++i) {
      const int m = m0 + wm + i * 16 + lr4;
      const int b = m >> 11, t = m & (SEQT - 1);
#pragma unroll
      for (int j = 0; j < 4; ++j) {
        const int n = n0 + wn + j * 16 + lc;
        const int h = n >> 6, d = n & 63;
        h16x4 o4;
#pragma unroll
        for (int r = 0; r < 4; ++r) o4[r] = (h16)acc[i][j][r];
        *(h16x4*)&Vt[((size_t)(b * NHEADS + h) * DKH + d) * SEQT + t] = o4;
      }
    }
  } else {
#pragma unroll
    for (int i = 0; i < 4; ++i) {
#pragma unroll
      for (int j = 0; j < 4; ++j) {
        const int n = n0 + wn + j * 16 + lc;
        const int h = n >> 6, d = n & 63;
#pragma unroll
        for (int r = 0; r < 4; ++r) {
          const int m = m0 + wm + i * 16 + lr4 + r;
          const int b = m >> 11, t = m & (SEQT - 1);
          float v = acc[i][j][r];
          float pv = __shfl_xor(v, 1);
          const int fi = d >> 1;
          float c = ctab[t * 32 + fi], s = stab[t * 32 + fi];
          float res = (d & 1) ? (v * c + pv * s) : (v * c - pv * s);
          if (which == 0) res *= QSCALE;   // fold sm_scale*log2e into Q
          h16* dst = (which == 0) ? Qb : Kb;
          dst[((size_t)(b * NHEADS + h) * SEQT + t) * DKH + d] = (h16)res;
        }
      }
    }
  }
}

// ---------------------------------------------------------------- attn ----
// R15 (best measured: 43.0us): QBLK=64, 4 waves, padded conflict-free LDS
// (strides 38/70 dw == 6 mod 32), balanced XCD map, split-phase
// single-buffer K/V prefetch, packed-f16 softmax (pk_max tree, f16 exp2,
// pk_add tile-sum), defer-max THR=9. This round's only change: the rescale
// branch is wave-uniform via __any (was per-lane divergent over a ~20-op
// body); body uses mnew=fmax(mrow,mx) so it stays exact.
// [Failed structural variants, do not retry: reg-prefetch K+V both (R6:
// spill), gll16 dbuf (R7: conflicts+occupancy), QBLK=128 4-wave (R9: TLP),
// 512-thread (R10: barrier grain), V-from-global (R12: uncoalesced),
// lsum-via-MFMA (R14: serial chain), split-K QBLK=32 (R16: 2x traffic).]
__global__ __launch_bounds__(256, 4) void attn_kernel(
    const h16* __restrict__ Qb, const h16* __restrict__ Kb,
    const h16* __restrict__ Vt, h16* __restrict__ Mg) {
  __shared__ h16 Kl[128][76];       // [key][d]  152B rows: 38 dw == 6 mod 32
  __shared__ h16 Vl[64][140];       // [d][key]  280B rows: 70 dw == 6 mod 32
  const int linear = blockIdx.x + 32 * blockIdx.y;
  const int v   = linear & 7;        // XCD class
  const int p   = linear >> 3;       // 0..127 position within class
  const int w   = p >> 5;            // 0..3
  const int c32 = p & 31;
  const int u   = (c32 + w) & 3;
  const int bh  = c32;
  const int qt  = (u == 0) ? v : (u == 1) ? (15 - v) : (u == 2) ? (16 + v) : (31 - v);
  const int b = bh >> 4, h = bh & 15;
  const int tid = threadIdx.x, lane = tid & 63, wv = tid >> 6;
  const int lr = lane & 15, lg = lane >> 4;
  const int q0 = qt * 64;
  const int qbase = q0 + wv * 16;
  const int q = qbase + lr;               // this lane's q-row
  const h16* Qp = Qb + ((size_t)bh * SEQT + qbase) * DKH;
  const h16* Kp = Kb + (size_t)bh * SEQT * DKH;
  const h16* Vp = Vt + (size_t)bh * DKH * SEQT;

  // Q as B-fragment of S^T = K·Q^T : col=q(lr), k=d(kk*32+lg*8+j)
  h16x8 qf[2];
#pragma unroll
  for (int kk = 0; kk < 2; ++kk)
    qf[kk] = *(const h16x8*)(Qp + lr * DKH + kk * 32 + lg * 8);

  float mrow = -3.0e38f, lsum = 0.f;
  f32x4 o[4];
  const f32x4 zero4 = {0.f, 0.f, 0.f, 0.f};
#pragma unroll
  for (int di = 0; di < 4; ++di) o[di] = zero4;

  const int sr = tid >> 2, sc = (tid & 3) * 16;
  uint4 ka0, ka1, ka2, ka3;   // K[kt+1] in flight (live across QK only)
  uint4 va0, va1, va2, va3;   // V[kt+1] in flight (live across softmax+PV)

#define KISSUE(k0_) {                                                      \
    const h16* kb_ = Kp + (size_t)(k0_) * DKH;                             \
    ka0 = *(const uint4*)(kb_ + (size_t)sr * DKH + sc);                    \
    ka1 = *(const uint4*)(kb_ + (size_t)sr * DKH + sc + 8);                \
    ka2 = *(const uint4*)(kb_ + (size_t)(64 + sr) * DKH + sc);             \
    ka3 = *(const uint4*)(kb_ + (size_t)(64 + sr) * DKH + sc + 8);         \
  }
#define KWRITE() {                                                         \
    *(uint4*)&Kl[sr][sc]          = ka0;                                   \
    *(uint4*)&Kl[sr][sc + 8]      = ka1;                                   \
    *(uint4*)&Kl[64 + sr][sc]     = ka2;                                   \
    *(uint4*)&Kl[64 + sr][sc + 8] = ka3;                                   \
  }
#define VISSUE(k0_) {                                                      \
    const h16* vb_ = Vp + (k0_);                                           \
    va0 = *(const uint4*)(vb_ + (size_t)sr * SEQT + sc);                   \
    va1 = *(const uint4*)(vb_ + (size_t)sr * SEQT + sc + 8);               \
    va2 = *(const uint4*)(vb_ + (size_t)sr * SEQT + 64 + sc);              \
    va3 = *(const uint4*)(vb_ + (size_t)sr * SEQT + 64 + sc + 8);          \
  }
#define VWRITE() {                                                         \
    *(uint4*)&Vl[sr][sc]          = va0;                                   \
    *(uint4*)&Vl[sr][sc + 8]      = va1;                                   \
    *(uint4*)&Vl[sr][64 + sc]     = va2;                                   \
    *(uint4*)&Vl[sr][64 + sc + 8] = va3;                                   \
  }

  // prologue: stage tile 0
  KISSUE(0); VISSUE(0);
  KWRITE(); VWRITE();
  __syncthreads();

  const int nkt = (qt >> 1) + 1;
  for (int kt = 0; kt < nkt; ++kt) {
    const int k0 = kt * 128;
    const bool more = (kt + 1 < nkt);

    // issue next K early: flies during QK
    if (more) { KISSUE(k0 + 128); __builtin_amdgcn_sched_barrier(0); }

    // S^T tile: lane holds score(q, key = k0 + ni*16 + lg*4 + r)
    f32x4 s[8];
    __builtin_amdgcn_s_setprio(1);
#pragma unroll
    for (int ni = 0; ni < 8; ++ni) {
      s[ni] = zero4;
#pragma unroll
      for (int kk = 0; kk < 2; ++kk) {
        h16x8 kf = *(const h16x8*)&Kl[ni * 16 + lr][kk * 32 + lg * 8];
        s[ni] = __builtin_amdgcn_mfma_f32_16x16x32_f16(kf, qf[kk], s[ni], 0, 0, 0);
      }
    }
    __builtin_amdgcn_s_setprio(0);

    __syncthreads();   // A: all waves done reading Kl
    if (more) {
      KWRITE();        // K[kt+1] -> Kl (vmcnt waits auto-inserted)
      VISSUE(k0 + 128); __builtin_amdgcn_sched_barrier(0);  // flies during softmax+PV
    }

    // causal mask only on the diagonal tile; scale pre-folded into Q
    if (kt == nkt - 1) {
#pragma unroll
      for (int ni = 0; ni < 8; ++ni)
#pragma unroll
        for (int r = 0; r < 4; ++r) {
          const int key = k0 + ni * 16 + lg * 4 + r;
          if (key > q) s[ni][r] = -3.0e38f;
        }
    }

    // S -> packed f16 (pkrtz saturates to +-65504, fine for masked -3e38)
    h16x4 s16[8];
#pragma unroll
    for (int ni = 0; ni < 8; ++ni) {
      h16x2 lo = pkrtz(s[ni][0], s[ni][1]);
      h16x2 hi = pkrtz(s[ni][2], s[ni][3]);
      s16[ni][0] = lo[0]; s16[ni][1] = lo[1]; s16[ni][2] = hi[0]; s16[ni][3] = hi[1];
    }

    // lane-local max: v_pk_max_f16 tree
    h16x4 t0 = __builtin_elementwise_max(s16[0], s16[1]);
    h16x4 t1 = __builtin_elementwise_max(s16[2], s16[3]);
    h16x4 t2 = __builtin_elementwise_max(s16[4], s16[5]);
    h16x4 t3 = __builtin_elementwise_max(s16[6], s16[7]);
    h16x4 t4 = __builtin_elementwise_max(__builtin_elementwise_max(t0, t1),
                                         __builtin_elementwise_max(t2, t3));
    h16 mh = t4[0] > t4[1] ? t4[0] : t4[1];
    h16 m2 = t4[2] > t4[3] ? t4[2] : t4[3];
    mh = mh > m2 ? mh : m2;
    float mx = (float)mh;
    mx = fmaxf(mx, __shfl_xor(mx, 16));
    mx = fmaxf(mx, __shfl_xor(mx, 32));
    // defer-max (THR = 9 -> P <= 512, f16 tile-sum <= 16384, no overflow).
    // Wave-uniform via __any: body exact (mnew=fmax), avoids divergent
    // dual-path execution over the rescale body.
    if (__any(mx > mrow + 9.0f)) {
      const float mnew = fmaxf(mrow, mx);
      const float scl = exp2f(mrow - mnew);
      mrow = mnew;
      lsum *= scl;
#pragma unroll
      for (int di = 0; di < 4; ++di)
#pragma unroll
        for (int r = 0; r < 4; ++r) o[di][r] *= scl;
    }

    // packed subtract + f16 exp2; pb feeds PV directly
    const h16 m16 = (h16)mrow;
    h16x4 mv; mv[0] = m16; mv[1] = m16; mv[2] = m16; mv[3] = m16;
    h16x4 pb[8];
#pragma unroll
    for (int ni = 0; ni < 8; ++ni) {
      h16x4 d = s16[ni] - mv;           // v_pk_add_f16 (neg)
      pb[ni][0] = hx2exp(d[0]); pb[ni][1] = hx2exp(d[1]);
      pb[ni][2] = hx2exp(d[2]); pb[ni][3] = hx2exp(d[3]);
    }

    // tile row-sum: v_pk_add_f16 tree, f32 finish + cross-lg shuffles
    {
      h16x4 a0 = pb[0] + pb[1];
      h16x4 a1 = pb[2] + pb[3];
      h16x4 a2 = pb[4] + pb[5];
      h16x4 a3 = pb[6] + pb[7];
      h16x4 a4 = (a0 + a1) + (a2 + a3);
      float rs = (float)a4[0] + (float)a4[1] + (float)a4[2] + (float)a4[3];
      rs += __shfl_xor(rs, 16);
      rs += __shfl_xor(rs, 32);
      lsum += rs;
    }

    // PV: O^T = V^T · P^T via 16x16x16; P stays in registers.
    __builtin_amdgcn_s_setprio(1);
#pragma unroll
    for (int ni = 0; ni < 8; ++ni) {
#pragma unroll
      for (int di = 0; di < 4; ++di) {
        h16x4 va = *(const h16x4*)&Vl[di * 16 + lr][ni * 16 + lg * 4];
        o[di] = __builtin_amdgcn_mfma_f32_16x16x16f16(va, pb[ni], o[di], 0, 0, 0);
      }
    }
    __builtin_amdgcn_s_setprio(0);

    __syncthreads();   // B: all waves done reading Vl; Kl[kt+1] visible
    if (more) VWRITE();   // V[kt+1] -> Vl; visible after next barrier A
  }
#undef KISSUE
#undef KWRITE
#undef VISSUE
#undef VWRITE

  // epilogue: normalize, bounce through LDS (reuse Kl) for coalesced write
  __syncthreads();
  const float inv = 1.0f / lsum;
#pragma unroll
  for (int di = 0; di < 4; ++di) {
    h16x2 lo = pkrtz(o[di][0] * inv, o[di][1] * inv);
    h16x2 hi = pkrtz(o[di][2] * inv, o[di][3] * inv);
    h16x4 o4; o4[0] = lo[0]; o4[1] = lo[1]; o4[2] = hi[0]; o4[3] = hi[1];
    *(h16x4*)&Kl[wv * 16 + lr][di * 16 + lg * 4] = o4;
  }
  __syncthreads();
  {
    const int row = tid >> 2, c0 = (tid & 3) * 16;
    h16* dst = Mg + ((size_t)(b * SEQT + q0 + row)) * DMODEL + h * DKH + c0;
    *(uint4*)dst       = *(const uint4*)&Kl[row][c0];
    *(uint4*)(dst + 8) = *(const uint4*)&Kl[row][c0 + 8];
  }
}

// ---------------------------------------------------------------- proj ----
__global__ __launch_bounds__(256, 2) void proj_kernel(
    const h16* __restrict__ Mg, const h16* __restrict__ wob, float* __restrict__ out) {
  __shared__ h16 Al[128 * 32], Bl[128 * 32];
  const int m0 = blockIdx.x * 128, n0 = blockIdx.y * 128;
  f32x4 acc[4][4];
  const f32x4 zero4 = {0.f, 0.f, 0.f, 0.f};
#pragma unroll
  for (int i = 0; i < 4; ++i)
#pragma unroll
    for (int j = 0; j < 4; ++j) acc[i][j] = zero4;

  gemm128_bt(Mg, wob, m0, n0, Al, Bl, acc);

  const int lane = threadIdx.x & 63, wv = threadIdx.x >> 6;
  const int wm = (wv >> 1) * 64, wn = (wv & 1) * 64;
  const int lr4 = ((lane >> 4) << 2), lc = lane & 15;
#pragma unroll
  for (int i = 0; i < 4; ++i)
#pragma unroll
    for (int j = 0; j < 4; ++j) {
      const int n = n0 + wn + j * 16 + lc;
#pragma unroll
      for (int r = 0; r < 4; ++r) {
        const int m = m0 + wm + i * 16 + lr4 + r;
        out[(size_t)m * DMODEL + n] = acc[i][j][r];
      }
    }
}

// -------------------------------------------------------------- launch ----
extern "C" void kernel_launch(void* const* d_in, const int* in_sizes, int n_in,
                              void* d_out, int out_size, void* d_ws, size_t ws_size,
                              hipStream_t stream) {
  (void)in_sizes; (void)n_in; (void)out_size; (void)ws_size;
  const float* x  = (const float*)d_in[0];
  const float* Wq = (const float*)d_in[1];
  const float* Wk = (const float*)d_in[2];
  const float* Wv = (const float*)d_in[3];
  const float* Wo = (const float*)d_in[4];
  float* out = (float*)d_out;

  char* w = (char*)d_ws;
  h16* xb  = (h16*)w; w += (size_t)MTOT * DMODEL * 2;
  h16* wqb = (h16*)w; w += (size_t)DMODEL * DMODEL * 2;
  h16* wkb = (h16*)w; w += (size_t)DMODEL * DMODEL * 2;
  h16* wvb = (h16*)w; w += (size_t)DMODEL * DMODEL * 2;
  h16* wob = (h16*)w; w += (size_t)DMODEL * DMODEL * 2;
  h16* Qb  = (h16*)w; w += (size_t)MTOT * DMODEL * 2;
  h16* Kb  = (h16*)w; w += (size_t)MTOT * DMODEL * 2;
  h16* Vt  = (h16*)w; w += (size_t)MTOT * DMODEL * 2;
  h16* Mg  = (h16*)w; w += (size_t)MTOT * DMODEL * 2;
  float* ctab = (float*)w; w += (size_t)SEQT * 32 * 4;
  float* stab = (float*)w; w += (size_t)SEQT * 32 * 4;

  prep_kernel<<<1024, 256, 0, stream>>>((const float4*)x, (const float4*)Wq, (const float4*)Wk,
                                        (const float4*)Wv, (const float4*)Wo,
                                        (h16x4*)xb, (h16x4*)wqb, (h16x4*)wkb, (h16x4*)wvb,
                                        (h16x4*)wob, ctab, stab);
  qkv_kernel<<<dim3(32, 8, 3), 256, 0, stream>>>(xb, wqb, wkb, wvb, ctab, stab, Qb, Kb, Vt);
  attn_kernel<<<dim3(32, 32), 256, 0, stream>>>(Qb, Kb, Vt, Mg);
  proj_kernel<<<dim3(32, 8), 256, 0, stream>>>(Mg, wob, out);
}